// Round 8
// baseline (393.507 us; speedup 1.0000x reference)
//
#include <hip/hip_runtime.h>
#include <hip/hip_fp16.h>

#define NUSERS 100000
#define NITEMS 50000
#define NTOT   150000   // NUSERS + NITEMS
#define DIM    64
#define NNZ    2000000
#define NLAYERS 3
#define NB     293      // buckets of 512 rows
#define BSH    9
#define BMSK   511
#define CAP    8192     // tmp bucket capacity (mean 6827, 16.5 sigma headroom)
#define ELLCAP 12288    // ELL bucket capacity (worst case ~11.4K)
#define NSLOTS (NB * 512)   // 150016 == padded row count (SLR)
#define SLR    NSLOTS       // rows per slice (padded)
#define NSL    8            // dim slices (8 dims = 16B fp16 each)
#define CHUNK  4096

typedef _Float16 half2_t __attribute__((ext_vector_type(2)));

__device__ __forceinline__ half2_t u2h(unsigned u) {
    union { unsigned u; half2_t h; } c; c.u = u; return c.h;
}

// ---------------------------------------------------------------------------
// block-wide inclusive scan, 512 threads
// ---------------------------------------------------------------------------
__device__ __forceinline__ int block_incl_scan512(int own, int* wsum, int t) {
    int incl = own;
    #pragma unroll
    for (int o = 1; o < 64; o <<= 1) {
        int v = __shfl_up(incl, o, 64);
        if ((t & 63) >= o) incl += v;
    }
    if ((t & 63) == 63) wsum[t >> 6] = incl;
    __syncthreads();
    if (t < 8) {
        int v = wsum[t];
        #pragma unroll
        for (int o = 1; o < 8; o <<= 1) {
            int u = __shfl_up(v, o, 64);
            if (t >= o) v += u;
        }
        wsum[t] = v;
    }
    __syncthreads();
    if (t >= 64) incl += wsum[(t >> 6) - 1];
    return incl;
}

// ---------------------------------------------------------------------------
// init: slice-major fp16 table. thread = (row, slice): reads 32B of the fp32
// row (coalesced 2KB/wave), writes 16B into slice s.
// ---------------------------------------------------------------------------
__global__ void lg_inits(const float* __restrict__ ue, const float* __restrict__ ie,
                         __half* __restrict__ T) {
    const int gid = blockIdx.x * blockDim.x + threadIdx.x;
    if (gid >= NTOT * NSL) return;
    const int r = gid >> 3;
    const int s = gid & 7;
    const float* src = (r < NUSERS) ? (ue + (size_t)r * DIM + s * 8)
                                    : (ie + (size_t)(r - NUSERS) * DIM + s * 8);
    const float4 f0 = *(const float4*)(src);
    const float4 f1 = *(const float4*)(src + 4);
    __half2 o[4];
    o[0] = __floats2half2_rn(f0.x, f0.y);
    o[1] = __floats2half2_rn(f0.z, f0.w);
    o[2] = __floats2half2_rn(f1.x, f1.y);
    o[3] = __floats2half2_rn(f1.z, f1.w);
    ((uint4*)(T + ((size_t)s * SLR + r) * 8))[0] = *(const uint4*)o;
}

// bcur[b] = b*CAP
__global__ void lg_binit(int* __restrict__ bcur) {
    const int t = blockIdx.x * blockDim.x + threadIdx.x;
    if (t < NB) bcur[t] = t * CAP;
}

// ---------------------------------------------------------------------------
// partition: chunk-aggregated scatter into fixed-capacity bucket segments.
// tmp entry: ((row&511)<<18 | col, val_f32)
// ---------------------------------------------------------------------------
__global__ __launch_bounds__(512) void lg_part(const int* __restrict__ row,
                                               const int* __restrict__ col,
                                               const float* __restrict__ vals,
                                               int* __restrict__ bcur,
                                               int2* __restrict__ tmp) {
    __shared__ int h[NB], off[NB], cnt2[NB], bs[NB];
    __shared__ int wsum[8];
    __shared__ unsigned short bk[CHUNK];
    __shared__ int2 stag[CHUNK];
    const int t = threadIdx.x;
    const int e0 = blockIdx.x * CHUNK;
    const int n = (NNZ - e0 < CHUNK) ? (NNZ - e0) : CHUNK;

    for (int i = t; i < NB; i += 512) { h[i] = 0; cnt2[i] = 0; }
    __syncthreads();
    for (int i = t; i < n; i += 512)
        atomicAdd(&h[row[e0 + i] >> BSH], 1);
    __syncthreads();
    const int own = (t < NB) ? h[t] : 0;
    const int incl = block_incl_scan512(own, wsum, t);
    if (t < NB) off[t] = incl - own;
    __syncthreads();
    for (int i = t; i < n; i += 512) {
        const int e = e0 + i;
        const int r = row[e];
        const int b = r >> BSH;
        const int k = atomicAdd(&cnt2[b], 1);
        const int s = off[b] + k;
        stag[s] = make_int2(((r & BMSK) << 18) | col[e], __float_as_int(vals[e]));
        bk[s] = (unsigned short)b;
    }
    __syncthreads();
    if (t < NB && own > 0) bs[t] = atomicAdd(&bcur[t], own);
    __syncthreads();
    for (int s = t; s < n; s += 512) {
        const int b = bk[s];
        tmp[bs[b] + (s - off[b])] = stag[s];
    }
}

// ---------------------------------------------------------------------------
// rowsort -> sliced-ELL. One block per 512-row bucket:
//  1. row-degree hist
//  2. degree counting sort -> rank (waves get near-equal-degree rows)
//  3. per-64-slot-group width = max deg (atomicMax), scan -> group bases
//  4. slot base = groupbase + (rank&63); entries at base + it*64 (interleaved,
//     so gather waves read 64 consecutive 8B entries per iteration)
//  5. scatter edges as (col*16 [byte offset in 16B-row slice], fp16(val))
// sbe[slot] = (base, deg); srid[slot] = row id or -1
// ---------------------------------------------------------------------------
__global__ __launch_bounds__(512) void lg_rsort(const int2* __restrict__ tmp,
                                                const int* __restrict__ bcur,
                                                int2* __restrict__ sbe,
                                                int* __restrict__ srid,
                                                int2* __restrict__ cedge) {
    __shared__ int h[512];
    __shared__ int dh[64], dcur[64];
    __shared__ int wmax[8], wbase8[8];
    const int b = blockIdx.x;
    const int t = threadIdx.x;
    const int s0 = b * CAP;
    const int s1 = bcur[b];
    const int e0 = b * ELLCAP;
    h[t] = 0;
    if (t < 64) dh[t] = 0;
    if (t < 8)  wmax[t] = 0;
    __syncthreads();
    for (int s = s0 + t; s < s1; s += 512)
        atomicAdd(&h[(tmp[s].x >> 18) & BMSK], 1);
    __syncthreads();
    const int own = h[t];
    const int bin = own < 63 ? own : 63;
    atomicAdd(&dh[bin], 1);
    __syncthreads();
    if (t < 64) {
        int v = dh[t];
        int inc = v;
        #pragma unroll
        for (int o = 1; o < 64; o <<= 1) {
            int u = __shfl_up(inc, o, 64);
            if (t >= o) inc += u;
        }
        dcur[t] = inc - v;
    }
    __syncthreads();
    const int rank = atomicAdd(&dcur[bin], 1);
    const int g = rank >> 6;
    atomicMax(&wmax[g], own);
    __syncthreads();
    if (t < 8) {
        int v = wmax[t];
        int inc = v;
        #pragma unroll
        for (int o = 1; o < 8; o <<= 1) {
            int u = __shfl_up(inc, o, 64);
            if (t >= o) inc += u;
        }
        wbase8[t] = e0 + 64 * (inc - v);
    }
    __syncthreads();
    const int base = wbase8[g] + (rank & 63);
    const int slot = (b << BSH) + rank;
    const int r = (b << BSH) + t;
    sbe[slot] = make_int2(base, own);
    srid[slot] = (r < NTOT) ? r : -1;
    __syncthreads();
    h[t] = base;                               // per-row ELL cursor, step 64
    __syncthreads();
    for (int s = s0 + t; s < s1; s += 512) {
        const int2 ev = tmp[s];
        const int rl = (ev.x >> 18) & BMSK;
        const int k = atomicAdd(&h[rl], 64);
        const float v = __int_as_float(ev.y);
        const __half hv = __float2half(v);
        const unsigned short hb = *(const unsigned short*)&hv;
        cedge[k] = make_int2((ev.x & 0x3FFFF) << 4, (int)(unsigned)hb);
    }
}

// ---------------------------------------------------------------------------
// dot: 8 dims (16B fp16) * fp16 val, fp32 accumulate via fdot2
// ---------------------------------------------------------------------------
__device__ __forceinline__ void dot8(float sum[8], const uint4& q, unsigned vh) {
#if __has_builtin(__builtin_amdgcn_fdot2)
    const half2_t vlo = u2h(vh);
    const half2_t vhi = u2h(vh << 16);
    const half2_t* hp = (const half2_t*)&q;
    #pragma unroll
    for (int k = 0; k < 4; ++k) {
        sum[2 * k]     = __builtin_amdgcn_fdot2(hp[k], vlo, sum[2 * k],     false);
        sum[2 * k + 1] = __builtin_amdgcn_fdot2(hp[k], vhi, sum[2 * k + 1], false);
    }
#else
    __half hv; *(unsigned short*)&hv = (unsigned short)(vh & 0xFFFF);
    const float v = __half2float(hv);
    const __half2* hp = (const __half2*)&q;
    #pragma unroll
    for (int k = 0; k < 4; ++k) {
        const float2 f = __half22float2(hp[k]);
        sum[2 * k]     += v * f.x;
        sum[2 * k + 1] += v * f.y;
    }
#endif
}

// ---------------------------------------------------------------------------
// ELL gather core: lane owns one (row, slice). Edge list interleaved with
// stride 64 -> wave reads 64 consecutive 8B entries per iteration (coalesced).
// Table read = 16B from the 2.4MB slice (XCD-L2-resident). 2-deep pipeline.
// ---------------------------------------------------------------------------
__device__ __forceinline__ void row_gather_ell(const int2* __restrict__ ce,
                                               const char* __restrict__ tb,
                                               int deg, int nit, float sum[8]) {
    #pragma unroll
    for (int k = 0; k < 8; ++k) sum[k] = 0.0f;
    if (nit <= 0) return;
    const int degm1 = deg > 0 ? deg - 1 : 0;
    const int2 c0 = ce[0];
    const bool v0 = 0 < deg;
    unsigned colb = v0 ? (unsigned)c0.x : 0u;
    unsigned vh   = v0 ? (unsigned)c0.y : 0u;
    uint4 q = *(const uint4*)(tb + colb);
    for (int it = 1; it < nit; ++it) {
        const int idx = (it < degm1 ? it : degm1) << 6;   // *64 entries
        const int2 c2 = ce[idx];
        const bool v2 = it < deg;
        const unsigned colb2 = v2 ? (unsigned)c2.x : 0u;
        const unsigned vh2   = v2 ? (unsigned)c2.y : 0u;
        const uint4 q2 = *(const uint4*)(tb + colb2);
        dot8(sum, q, vh);
        q = q2; vh = vh2;
    }
    dot8(sum, q, vh);
}

__device__ __forceinline__ int wave_max(int v) {
    #pragma unroll
    for (int m = 1; m < 64; m <<= 1) {
        const int o = __shfl_xor(v, m, 64);
        v = v > o ? v : o;
    }
    return v;
}

// mid layer: nxtT[s][rid] = fp16(A * curT[s])   -- slice s = blockIdx & 7
__global__ __launch_bounds__(256) void lg_gmid(const int2* __restrict__ sbe,
                                               const int* __restrict__ srid,
                                               const int2* __restrict__ cedge,
                                               const __half* __restrict__ curT,
                                               __half* __restrict__ nxtT) {
    const int s = blockIdx.x & 7;
    const int slot = (blockIdx.x >> 3) * 256 + threadIdx.x;   // < NSLOTS exactly
    const char* tb = (const char*)(curT + (size_t)s * SLR * 8);
    const int2 bd = sbe[slot];
    const int rid = srid[slot];
    const int deg = bd.y;
    const int nit = wave_max(deg);
    float sum[8];
    row_gather_ell(cedge + bd.x, tb, deg, nit, sum);
    if (rid >= 0) {
        __half2 o[4];
        #pragma unroll
        for (int k = 0; k < 4; ++k) o[k] = __floats2half2_rn(sum[2 * k], sum[2 * k + 1]);
        ((uint4*)(nxtT + ((size_t)s * SLR + rid) * 8))[0] = *(const uint4*)o;
    }
}

// last layer, fused: acc[rid][8s..8s+8) = 0.25*(b0+b1+b2+A*b2)  (fp32 out)
__global__ __launch_bounds__(256) void lg_glast(const int2* __restrict__ sbe,
                                                const int* __restrict__ srid,
                                                const int2* __restrict__ cedge,
                                                const __half* __restrict__ b0,
                                                const __half* __restrict__ b1,
                                                const __half* __restrict__ b2,
                                                float* __restrict__ acc) {
    const int s = blockIdx.x & 7;
    const int slot = (blockIdx.x >> 3) * 256 + threadIdx.x;
    const char* tb = (const char*)(b2 + (size_t)s * SLR * 8);
    const int2 bd = sbe[slot];
    const int rid = srid[slot];
    const int deg = bd.y;
    const int nit = wave_max(deg);
    float sum[8];
    row_gather_ell(cedge + bd.x, tb, deg, nit, sum);
    if (rid >= 0) {
        const size_t sb = ((size_t)s * SLR + rid) * 8;
        const uint4 q0 = *(const uint4*)(b0 + sb);
        const uint4 q1 = *(const uint4*)(b1 + sb);
        const uint4 q2 = *(const uint4*)(b2 + sb);
        const __half2* h0 = (const __half2*)&q0;
        const __half2* h1 = (const __half2*)&q1;
        const __half2* h2 = (const __half2*)&q2;
        float out[8];
        #pragma unroll
        for (int k = 0; k < 4; ++k) {
            const float2 f0 = __half22float2(h0[k]);
            const float2 f1 = __half22float2(h1[k]);
            const float2 f2 = __half22float2(h2[k]);
            out[2 * k]     = 0.25f * (f0.x + f1.x + f2.x + sum[2 * k]);
            out[2 * k + 1] = 0.25f * (f0.y + f1.y + f2.y + sum[2 * k + 1]);
        }
        float* dst = acc + (size_t)rid * DIM + s * 8;
        *(float4*)(dst)     = make_float4(out[0], out[1], out[2], out[3]);
        *(float4*)(dst + 4) = make_float4(out[4], out[5], out[6], out[7]);
    }
}

// ---------------------------------------------------------------------------
// Fallback (round-1) kernels
// ---------------------------------------------------------------------------
__global__ void lg_init2(const float* __restrict__ ue, const float* __restrict__ ie,
                         float* __restrict__ cur, float* __restrict__ acc) {
    const int total4 = NTOT * DIM / 4;
    const int ubound4 = NUSERS * DIM / 4;
    const float4* ue4 = (const float4*)ue;
    const float4* ie4 = (const float4*)ie;
    float4* cur4 = (float4*)cur;
    float4* acc4 = (float4*)acc;
    for (int i = blockIdx.x * blockDim.x + threadIdx.x; i < total4;
         i += gridDim.x * blockDim.x) {
        float4 v = (i < ubound4) ? ue4[i] : ie4[i - ubound4];
        cur4[i] = v;
        float4 a;
        a.x = 0.25f * v.x; a.y = 0.25f * v.y; a.z = 0.25f * v.z; a.w = 0.25f * v.w;
        acc4[i] = a;
    }
}

__global__ void lg_scatter(const float* __restrict__ cur, const float* __restrict__ vals,
                           const int* __restrict__ row, const int* __restrict__ col,
                           float* __restrict__ next) {
    const long long total = (long long)NNZ * 64;
    for (long long t = blockIdx.x * (long long)blockDim.x + threadIdx.x; t < total;
         t += (long long)gridDim.x * blockDim.x) {
        const int e    = (int)(t >> 6);
        const int lane = (int)(t & 63);
        const float m  = cur[(long long)col[e] * DIM + lane] * vals[e];
        atomicAdd(&next[(long long)row[e] * DIM + lane], m);
    }
}

__global__ void lg_axpy(const float* __restrict__ next, float* __restrict__ acc) {
    const int total4 = NTOT * DIM / 4;
    const float4* n4 = (const float4*)next;
    float4* a4 = (float4*)acc;
    for (int i = blockIdx.x * blockDim.x + threadIdx.x; i < total4;
         i += gridDim.x * blockDim.x) {
        float4 n = n4[i];
        float4 a = a4[i];
        a.x += 0.25f * n.x; a.y += 0.25f * n.y; a.z += 0.25f * n.z; a.w += 0.25f * n.w;
        a4[i] = a;
    }
}

extern "C" void kernel_launch(void* const* d_in, const int* in_sizes, int n_in,
                              void* d_out, int out_size, void* d_ws, size_t ws_size,
                              hipStream_t stream) {
    const float* ue   = (const float*)d_in[0];
    const float* ie   = (const float*)d_in[1];
    const float* vals = (const float*)d_in[2];
    const int*   row  = (const int*)d_in[3];
    const int*   col  = (const int*)d_in[4];

    float* acc = (float*)d_out;

    const size_t TBL = (size_t)SLR * DIM;        // halves per slice-major table

    // workspace layout
    __half* b0   = (__half*)d_ws;                // 19.2 MB  (slice-major)
    __half* b1   = b0 + TBL;                     // 19.2 MB
    __half* b2   = b1 + TBL;                     // 19.2 MB
    int2* tmp    = (int2*)(b2 + TBL);            // NB*CAP int2    = 19.2 MB
    int2* cedge  = tmp + (size_t)NB * CAP;       // NB*ELLCAP int2 = 28.8 MB
    int2* sbe    = cedge + (size_t)NB * ELLCAP;  // 1.2 MB
    int*  srid   = (int*)(sbe + NSLOTS);         // 0.6 MB
    int*  bcur   = srid + NSLOTS;                // NB
    const size_t need = (size_t)((char*)(bcur + NB) - (char*)d_ws);   // ~108 MB

    if (ws_size >= need) {
        const int nchunks = (NNZ + CHUNK - 1) / CHUNK;   // 489
        const int iblocks = (NTOT * NSL + 255) / 256;    // 4688
        const int gblocks = (NSLOTS / 256) * NSL;        // 586*8 = 4688

        lg_inits<<<iblocks, 256, 0, stream>>>(ue, ie, b0);
        lg_binit<<<1, 512, 0, stream>>>(bcur);
        lg_part<<<nchunks, 512, 0, stream>>>(row, col, vals, bcur, tmp);
        lg_rsort<<<NB, 512, 0, stream>>>(tmp, bcur, sbe, srid, cedge);

        lg_gmid <<<gblocks, 256, 0, stream>>>(sbe, srid, cedge, b0, b1);
        lg_gmid <<<gblocks, 256, 0, stream>>>(sbe, srid, cedge, b1, b2);
        lg_glast<<<gblocks, 256, 0, stream>>>(sbe, srid, cedge, b0, b1, b2, acc);
    } else {
        // minimal fallback: round-1 scatter path
        const size_t EMB = (size_t)NTOT * DIM;
        float* cur = (float*)d_ws;
        float* nxt = cur + EMB;
        const size_t buf_bytes = EMB * sizeof(float);
        lg_init2<<<1024, 256, 0, stream>>>(ue, ie, cur, acc);
        for (int l = 0; l < NLAYERS; ++l) {
            hipMemsetAsync(nxt, 0, buf_bytes, stream);
            lg_scatter<<<8192, 256, 0, stream>>>(cur, vals, row, col, nxt);
            lg_axpy<<<1024, 256, 0, stream>>>(nxt, acc);
            float* t = cur; cur = nxt; nxt = t;
        }
    }
}

// Round 9
// 210.493 us; speedup vs baseline: 1.8695x; 1.8695x over previous
//
#include <hip/hip_runtime.h>
#include <hip/hip_fp16.h>

#define NUSERS 100000
#define NITEMS 50000
#define NTOT   150000   // NUSERS + NITEMS
#define DIM    64
#define NNZ    2000000
#define NLAYERS 3
#define NB     293      // buckets of 512 rows: 293*512 = 150016 >= NTOT
#define BSH    9        // bucket shift (512 rows)
#define BMSK   511
#define CAP    8192     // fixed bucket capacity (mean 6827, sigma 82.5 -> 16.5 sigma)
#define NSLOTS (NB * 512)
#define CHUNK  4096     // edges per partition block

typedef _Float16 half2_t __attribute__((ext_vector_type(2)));

__device__ __forceinline__ half2_t u2h(unsigned u) {
    union { unsigned u; half2_t h; } c; c.u = u; return c.h;
}

// ---------------------------------------------------------------------------
// block-wide inclusive scan, 512 threads
// ---------------------------------------------------------------------------
__device__ __forceinline__ int block_incl_scan512(int own, int* wsum, int t) {
    int incl = own;
    #pragma unroll
    for (int o = 1; o < 64; o <<= 1) {
        int v = __shfl_up(incl, o, 64);
        if ((t & 63) >= o) incl += v;
    }
    if ((t & 63) == 63) wsum[t >> 6] = incl;
    __syncthreads();
    if (t < 8) {
        int v = wsum[t];
        #pragma unroll
        for (int o = 1; o < 8; o <<= 1) {
            int u = __shfl_up(v, o, 64);
            if (t >= o) v += u;
        }
        wsum[t] = v;
    }
    __syncthreads();
    if (t >= 64) incl += wsum[(t >> 6) - 1];
    return incl;
}

// ---------------------------------------------------------------------------
// init: b0 = fp16(concat(user_emb, item_emb))  (row-major, 128B rows)
// ---------------------------------------------------------------------------
__global__ void lg_inith(const float* __restrict__ ue, const float* __restrict__ ie,
                         __half* __restrict__ b0) {
    const int total4 = NTOT * DIM / 4;
    const int ubound4 = NUSERS * DIM / 4;
    const float4* ue4 = (const float4*)ue;
    const float4* ie4 = (const float4*)ie;
    uint2* out = (uint2*)b0;
    for (int i = blockIdx.x * blockDim.x + threadIdx.x; i < total4;
         i += gridDim.x * blockDim.x) {
        const float4 v = (i < ubound4) ? ue4[i] : ie4[i - ubound4];
        __half2 h0 = __floats2half2_rn(v.x, v.y);
        __half2 h1 = __floats2half2_rn(v.z, v.w);
        uint2 u;
        u.x = *(const unsigned int*)&h0;
        u.y = *(const unsigned int*)&h1;
        out[i] = u;
    }
}

// bcur[b] = b*CAP (fixed-capacity bucket segments; no hist/scan needed)
__global__ void lg_binit(int* __restrict__ bcur) {
    const int t = blockIdx.x * blockDim.x + threadIdx.x;
    if (t < NB) bcur[t] = t * CAP;
}

// ---------------------------------------------------------------------------
// partition: chunk-aggregated scatter into fixed-capacity bucket segments.
// LDS-stage CHUNK edges grouped by bucket, claim each bucket run with ONE
// global atomic, flush coalesced. tmp entry: ((row&511)<<18 | col, val_f32).
// ---------------------------------------------------------------------------
__global__ __launch_bounds__(512) void lg_part(const int* __restrict__ row,
                                               const int* __restrict__ col,
                                               const float* __restrict__ vals,
                                               int* __restrict__ bcur,
                                               int2* __restrict__ tmp) {
    __shared__ int h[NB], off[NB], cnt2[NB], bs[NB];
    __shared__ int wsum[8];
    __shared__ unsigned short bk[CHUNK];
    __shared__ int2 stag[CHUNK];
    const int t = threadIdx.x;
    const int e0 = blockIdx.x * CHUNK;
    const int n = (NNZ - e0 < CHUNK) ? (NNZ - e0) : CHUNK;

    for (int i = t; i < NB; i += 512) { h[i] = 0; cnt2[i] = 0; }
    __syncthreads();
    for (int i = t; i < n; i += 512)
        atomicAdd(&h[row[e0 + i] >> BSH], 1);
    __syncthreads();
    const int own = (t < NB) ? h[t] : 0;
    const int incl = block_incl_scan512(own, wsum, t);
    if (t < NB) off[t] = incl - own;
    __syncthreads();
    for (int i = t; i < n; i += 512) {
        const int e = e0 + i;
        const int r = row[e];
        const int b = r >> BSH;
        const int k = atomicAdd(&cnt2[b], 1);
        const int s = off[b] + k;
        stag[s] = make_int2(((r & BMSK) << 18) | col[e], __float_as_int(vals[e]));
        bk[s] = (unsigned short)b;
    }
    __syncthreads();
    if (t < NB && own > 0) bs[t] = atomicAdd(&bcur[t], own);
    __syncthreads();
    for (int s = t; s < n; s += 512) {
        const int b = bk[s];
        tmp[bs[b] + (s - off[b])] = stag[s];
    }
}

// ---------------------------------------------------------------------------
// rowsort: one block per 512-row bucket.
//  - LDS row-hist + scan -> per-row [beg,end) within the bucket's cedge region
//  - LDS counting sort by degree (bins 0..63) -> slot order; waves get
//    near-equal-degree rows (lane-idle from max-deg sync ~0)
//  - scatter edges into cedge as (col<<7 [byte offset], fp16(val) bits)
// sbe[slot]=(beg,end), srid[slot]=row id (-1 for ghost rows >= NTOT)
// ---------------------------------------------------------------------------
__global__ __launch_bounds__(512) void lg_rsort(const int2* __restrict__ tmp,
                                                const int* __restrict__ bcur,
                                                int2* __restrict__ sbe,
                                                int* __restrict__ srid,
                                                int2* __restrict__ cedge) {
    __shared__ int h[512];
    __shared__ int wsum[8];
    __shared__ int dh[64], dcur[64];
    const int b = blockIdx.x;
    const int t = threadIdx.x;
    const int s0 = b * CAP;
    const int s1 = bcur[b];                    // s0 + bucket count (post-part)
    h[t] = 0;
    if (t < 64) dh[t] = 0;
    __syncthreads();
    for (int s = s0 + t; s < s1; s += 512)
        atomicAdd(&h[(tmp[s].x >> 18) & BMSK], 1);
    __syncthreads();
    const int own = h[t];
    const int incl = block_incl_scan512(own, wsum, t);
    const int excl = incl - own;
    const int beg = s0 + excl;
    // degree counting sort
    const int bin = own < 63 ? own : 63;
    atomicAdd(&dh[bin], 1);
    __syncthreads();
    if (t < 64) {
        int v = dh[t];
        int inc = v;
        #pragma unroll
        for (int o = 1; o < 64; o <<= 1) {
            int u = __shfl_up(inc, o, 64);
            if (t >= o) inc += u;
        }
        dcur[t] = inc - v;                     // exclusive base of bin
    }
    __syncthreads();
    const int rank = atomicAdd(&dcur[bin], 1);
    const int r = (b << BSH) + t;
    const int slot = (b << BSH) + rank;
    sbe[slot] = make_int2(beg, beg + own);
    srid[slot] = (r < NTOT) ? r : -1;
    __syncthreads();
    h[t] = excl;                               // reuse as per-row cursor
    __syncthreads();
    for (int s = s0 + t; s < s1; s += 512) {
        const int2 ev = tmp[s];
        const int rl = (ev.x >> 18) & BMSK;
        const int k = atomicAdd(&h[rl], 1);
        const float v = __int_as_float(ev.y);
        const __half hv = __float2half(v);
        const unsigned short hb = *(const unsigned short*)&hv;
        cedge[s0 + k] = make_int2((ev.x & 0x3FFFF) << 7, (int)(unsigned)hb);
    }
}

// ---------------------------------------------------------------------------
// dot: 8 dims (16B fp16) * val, fp32 accumulate via fdot2. vh = fp16 bits in
// low half; vh<<16 selects odd elements.
// ---------------------------------------------------------------------------
__device__ __forceinline__ void dot8(float sum[8], const uint4& q, unsigned vh) {
#if __has_builtin(__builtin_amdgcn_fdot2)
    const half2_t vlo = u2h(vh);
    const half2_t vhi = u2h(vh << 16);
    const half2_t* hp = (const half2_t*)&q;
    #pragma unroll
    for (int k = 0; k < 4; ++k) {
        sum[2 * k]     = __builtin_amdgcn_fdot2(hp[k], vlo, sum[2 * k],     false);
        sum[2 * k + 1] = __builtin_amdgcn_fdot2(hp[k], vhi, sum[2 * k + 1], false);
    }
#else
    __half hv; *(unsigned short*)&hv = (unsigned short)(vh & 0xFFFF);
    const float v = __half2float(hv);
    const __half2* hp = (const __half2*)&q;
    #pragma unroll
    for (int k = 0; k < 4; ++k) {
        const float2 f = __half22float2(hp[k]);
        sum[2 * k]     += v * f.x;
        sum[2 * k + 1] += v * f.y;
    }
#endif
}

// ---------------------------------------------------------------------------
// gather core, 4-deep MLP: 8-lane group owns one row; lane d covers dims
// [8d,8d+8). Edges processed in chunks of 4: all 4 edge entries + all 4
// table lines are issued before any dot consumes them -> 4 outstanding
// 128B line requests per row-group (was ~2). Clamped-index + masked-val
// makes over-reads past deg safe (adds 0).
// ---------------------------------------------------------------------------
__device__ __forceinline__ void row_gather4(const int2* __restrict__ ce,
                                            const char* __restrict__ tb,
                                            int deg, int nit, float sum[8]) {
    #pragma unroll
    for (int k = 0; k < 8; ++k) sum[k] = 0.0f;
    if (nit <= 0) return;
    const int degm1 = deg > 0 ? deg - 1 : 0;
    for (int it0 = 0; it0 < nit; it0 += 4) {
        unsigned vh[4];
        uint4 q[4];
        #pragma unroll
        for (int j = 0; j < 4; ++j) {
            const int it = it0 + j;
            const int idx = it < degm1 ? it : degm1;
            const int2 c = ce[idx];
            const bool valid = it < deg;
            const unsigned colb = valid ? (unsigned)c.x : 0u;
            vh[j] = valid ? (unsigned)c.y : 0u;
            q[j] = *(const uint4*)(tb + colb);
        }
        #pragma unroll
        for (int j = 0; j < 4; ++j) dot8(sum, q[j], vh[j]);
    }
}

// mid layer: nxt = fp16(A * cur)
__global__ __launch_bounds__(256) void lg_gmid(const int2* __restrict__ sbe,
                                               const int* __restrict__ srid,
                                               const int2* __restrict__ cedge,
                                               const __half* __restrict__ cur,
                                               __half* __restrict__ nxt) {
    const int gid = blockIdx.x * 256 + threadIdx.x;
    const int slot = ((gid >> 6) << 3) + ((gid & 63) >> 3);
    const int d = gid & 7;
    const int2 pe = sbe[slot];
    const int rid = srid[slot];
    const int deg = pe.y - pe.x;
    const int nit = __shfl(deg, 63, 64);       // wave max (degree-sorted)
    float s[8];
    row_gather4(cedge + pe.x, (const char*)cur + d * 16, deg, nit, s);
    if (rid >= 0) {
        __half2 o[4];
        #pragma unroll
        for (int k = 0; k < 4; ++k) o[k] = __floats2half2_rn(s[2 * k], s[2 * k + 1]);
        ((uint4*)(nxt + ((size_t)rid << 6)))[d] = *(const uint4*)o;
    }
}

// last layer, fused: acc = 0.25*(b0 + b1 + b2 + A*b2)   (fp32 output)
__global__ __launch_bounds__(256) void lg_glast(const int2* __restrict__ sbe,
                                                const int* __restrict__ srid,
                                                const int2* __restrict__ cedge,
                                                const __half* __restrict__ b0,
                                                const __half* __restrict__ b1,
                                                const __half* __restrict__ b2,
                                                float* __restrict__ acc) {
    const int gid = blockIdx.x * 256 + threadIdx.x;
    const int slot = ((gid >> 6) << 3) + ((gid & 63) >> 3);
    const int d = gid & 7;
    const int2 pe = sbe[slot];
    const int rid = srid[slot];
    const int deg = pe.y - pe.x;
    const int nit = __shfl(deg, 63, 64);
    float s[8];
    row_gather4(cedge + pe.x, (const char*)b2 + d * 16, deg, nit, s);
    if (rid >= 0) {
        const size_t base = (size_t)rid << 6;
        const uint4 q0 = ((const uint4*)(b0 + base))[d];
        const uint4 q1 = ((const uint4*)(b1 + base))[d];
        const uint4 q2 = ((const uint4*)(b2 + base))[d];
        const __half2* h0 = (const __half2*)&q0;
        const __half2* h1 = (const __half2*)&q1;
        const __half2* h2 = (const __half2*)&q2;
        float out[8];
        #pragma unroll
        for (int k = 0; k < 4; ++k) {
            const float2 f0 = __half22float2(h0[k]);
            const float2 f1 = __half22float2(h1[k]);
            const float2 f2 = __half22float2(h2[k]);
            out[2 * k]     = 0.25f * (f0.x + f1.x + f2.x + s[2 * k]);
            out[2 * k + 1] = 0.25f * (f0.y + f1.y + f2.y + s[2 * k + 1]);
        }
        float* dst = acc + base + (size_t)d * 8;
        *(float4*)(dst)     = make_float4(out[0], out[1], out[2], out[3]);
        *(float4*)(dst + 4) = make_float4(out[4], out[5], out[6], out[7]);
    }
}

// ---------------------------------------------------------------------------
// Fallback (round-1) kernels: edge-parallel scatter with fp32 atomics
// ---------------------------------------------------------------------------
__global__ void lg_init2(const float* __restrict__ ue, const float* __restrict__ ie,
                         float* __restrict__ cur, float* __restrict__ acc) {
    const int total4 = NTOT * DIM / 4;
    const int ubound4 = NUSERS * DIM / 4;
    const float4* ue4 = (const float4*)ue;
    const float4* ie4 = (const float4*)ie;
    float4* cur4 = (float4*)cur;
    float4* acc4 = (float4*)acc;
    for (int i = blockIdx.x * blockDim.x + threadIdx.x; i < total4;
         i += gridDim.x * blockDim.x) {
        float4 v = (i < ubound4) ? ue4[i] : ie4[i - ubound4];
        cur4[i] = v;
        float4 a;
        a.x = 0.25f * v.x; a.y = 0.25f * v.y; a.z = 0.25f * v.z; a.w = 0.25f * v.w;
        acc4[i] = a;
    }
}

__global__ void lg_scatter(const float* __restrict__ cur, const float* __restrict__ vals,
                           const int* __restrict__ row, const int* __restrict__ col,
                           float* __restrict__ next) {
    const long long total = (long long)NNZ * 64;
    for (long long t = blockIdx.x * (long long)blockDim.x + threadIdx.x; t < total;
         t += (long long)gridDim.x * blockDim.x) {
        const int e    = (int)(t >> 6);
        const int lane = (int)(t & 63);
        const float m  = cur[(long long)col[e] * DIM + lane] * vals[e];
        atomicAdd(&next[(long long)row[e] * DIM + lane], m);
    }
}

__global__ void lg_axpy(const float* __restrict__ next, float* __restrict__ acc) {
    const int total4 = NTOT * DIM / 4;
    const float4* n4 = (const float4*)next;
    float4* a4 = (float4*)acc;
    for (int i = blockIdx.x * blockDim.x + threadIdx.x; i < total4;
         i += gridDim.x * blockDim.x) {
        float4 n = n4[i];
        float4 a = a4[i];
        a.x += 0.25f * n.x; a.y += 0.25f * n.y; a.z += 0.25f * n.z; a.w += 0.25f * n.w;
        a4[i] = a;
    }
}

extern "C" void kernel_launch(void* const* d_in, const int* in_sizes, int n_in,
                              void* d_out, int out_size, void* d_ws, size_t ws_size,
                              hipStream_t stream) {
    const float* ue   = (const float*)d_in[0];
    const float* ie   = (const float*)d_in[1];
    const float* vals = (const float*)d_in[2];
    const int*   row  = (const int*)d_in[3];
    const int*   col  = (const int*)d_in[4];

    float* acc = (float*)d_out;

    const size_t EMB = (size_t)NTOT * DIM;       // 9.6M elements

    // workspace layout
    __half* b0   = (__half*)d_ws;                // 19.2 MB
    __half* b1   = b0 + EMB;                     // 19.2 MB
    __half* b2   = b1 + EMB;                     // 19.2 MB
    int2* tmp    = (int2*)(b2 + EMB);            // NB*CAP int2 = 19.2 MB
    int2* cedge  = tmp + (size_t)NB * CAP;       // 19.2 MB
    int2* sbe    = cedge + (size_t)NB * CAP;     // NSLOTS int2 = 1.2 MB
    int*  srid   = (int*)(sbe + NSLOTS);         // 0.6 MB
    int*  bcur   = srid + NSLOTS;                // NB
    const size_t need = (size_t)((char*)(bcur + NB) - (char*)d_ws);   // ~97.8 MB

    if (ws_size >= need) {
        const int nchunks = (NNZ + CHUNK - 1) / CHUNK;   // 489
        const int gblocks = NSLOTS * 8 / 256;            // 4688, exact

        lg_inith<<<1024, 256, 0, stream>>>(ue, ie, b0);
        lg_binit<<<1, 512, 0, stream>>>(bcur);
        lg_part<<<nchunks, 512, 0, stream>>>(row, col, vals, bcur, tmp);
        lg_rsort<<<NB, 512, 0, stream>>>(tmp, bcur, sbe, srid, cedge);

        lg_gmid <<<gblocks, 256, 0, stream>>>(sbe, srid, cedge, b0, b1);
        lg_gmid <<<gblocks, 256, 0, stream>>>(sbe, srid, cedge, b1, b2);
        lg_glast<<<gblocks, 256, 0, stream>>>(sbe, srid, cedge, b0, b1, b2, acc);
    } else {
        // minimal fallback: round-1 scatter path (2 x 38.4 MB fp32)
        float* cur = (float*)d_ws;
        float* nxt = cur + EMB;
        const size_t buf_bytes = EMB * sizeof(float);
        lg_init2<<<1024, 256, 0, stream>>>(ue, ie, cur, acc);
        for (int l = 0; l < NLAYERS; ++l) {
            hipMemsetAsync(nxt, 0, buf_bytes, stream);
            lg_scatter<<<8192, 256, 0, stream>>>(cur, vals, row, col, nxt);
            lg_axpy<<<1024, 256, 0, stream>>>(nxt, acc);
            float* t = cur; cur = nxt; nxt = t;
        }
    }
}

// Round 10
// 209.559 us; speedup vs baseline: 1.8778x; 1.0045x over previous
//
#include <hip/hip_runtime.h>
#include <hip/hip_fp16.h>

#define NUSERS 100000
#define NITEMS 50000
#define NTOT   150000   // NUSERS + NITEMS
#define DIM    64
#define NNZ    2000000
#define NLAYERS 3
#define NB     293      // buckets of 512 rows: 293*512 = 150016 >= NTOT
#define BSH    9        // bucket shift (512 rows)
#define BMSK   511
#define CAP    8192     // fixed bucket capacity (mean 6827, sigma 82.5 -> 16.5 sigma)
#define NSLOTS (NB * 512)
#define CHUNK  4096     // edges per partition block

typedef _Float16 half2_t __attribute__((ext_vector_type(2)));

__device__ __forceinline__ half2_t u2h(unsigned u) {
    union { unsigned u; half2_t h; } c; c.u = u; return c.h;
}

// ---------------------------------------------------------------------------
// block-wide inclusive scan, 512 threads
// ---------------------------------------------------------------------------
__device__ __forceinline__ int block_incl_scan512(int own, int* wsum, int t) {
    int incl = own;
    #pragma unroll
    for (int o = 1; o < 64; o <<= 1) {
        int v = __shfl_up(incl, o, 64);
        if ((t & 63) >= o) incl += v;
    }
    if ((t & 63) == 63) wsum[t >> 6] = incl;
    __syncthreads();
    if (t < 8) {
        int v = wsum[t];
        #pragma unroll
        for (int o = 1; o < 8; o <<= 1) {
            int u = __shfl_up(v, o, 64);
            if (t >= o) v += u;
        }
        wsum[t] = v;
    }
    __syncthreads();
    if (t >= 64) incl += wsum[(t >> 6) - 1];
    return incl;
}

// ---------------------------------------------------------------------------
// init: b0 = fp16(concat(user_emb, item_emb))  (row-major, 128B rows)
// ---------------------------------------------------------------------------
__global__ void lg_inith(const float* __restrict__ ue, const float* __restrict__ ie,
                         __half* __restrict__ b0) {
    const int total4 = NTOT * DIM / 4;
    const int ubound4 = NUSERS * DIM / 4;
    const float4* ue4 = (const float4*)ue;
    const float4* ie4 = (const float4*)ie;
    uint2* out = (uint2*)b0;
    for (int i = blockIdx.x * blockDim.x + threadIdx.x; i < total4;
         i += gridDim.x * blockDim.x) {
        const float4 v = (i < ubound4) ? ue4[i] : ie4[i - ubound4];
        __half2 h0 = __floats2half2_rn(v.x, v.y);
        __half2 h1 = __floats2half2_rn(v.z, v.w);
        uint2 u;
        u.x = *(const unsigned int*)&h0;
        u.y = *(const unsigned int*)&h1;
        out[i] = u;
    }
}

// bcur[b] = b*CAP
__global__ void lg_binit(int* __restrict__ bcur) {
    const int t = blockIdx.x * blockDim.x + threadIdx.x;
    if (t < NB) bcur[t] = t * CAP;
}

// ---------------------------------------------------------------------------
// partition: chunk-aggregated scatter into fixed-capacity bucket segments.
// tmp entry: ((row&511)<<18 | col, val_f32)
// ---------------------------------------------------------------------------
__global__ __launch_bounds__(512) void lg_part(const int* __restrict__ row,
                                               const int* __restrict__ col,
                                               const float* __restrict__ vals,
                                               int* __restrict__ bcur,
                                               int2* __restrict__ tmp) {
    __shared__ int h[NB], off[NB], cnt2[NB], bs[NB];
    __shared__ int wsum[8];
    __shared__ unsigned short bk[CHUNK];
    __shared__ int2 stag[CHUNK];
    const int t = threadIdx.x;
    const int e0 = blockIdx.x * CHUNK;
    const int n = (NNZ - e0 < CHUNK) ? (NNZ - e0) : CHUNK;

    for (int i = t; i < NB; i += 512) { h[i] = 0; cnt2[i] = 0; }
    __syncthreads();
    for (int i = t; i < n; i += 512)
        atomicAdd(&h[row[e0 + i] >> BSH], 1);
    __syncthreads();
    const int own = (t < NB) ? h[t] : 0;
    const int incl = block_incl_scan512(own, wsum, t);
    if (t < NB) off[t] = incl - own;
    __syncthreads();
    for (int i = t; i < n; i += 512) {
        const int e = e0 + i;
        const int r = row[e];
        const int b = r >> BSH;
        const int k = atomicAdd(&cnt2[b], 1);
        const int s = off[b] + k;
        stag[s] = make_int2(((r & BMSK) << 18) | col[e], __float_as_int(vals[e]));
        bk[s] = (unsigned short)b;
    }
    __syncthreads();
    if (t < NB && own > 0) bs[t] = atomicAdd(&bcur[t], own);
    __syncthreads();
    for (int s = t; s < n; s += 512) {
        const int b = bk[s];
        tmp[bs[b] + (s - off[b])] = stag[s];
    }
}

// ---------------------------------------------------------------------------
// rowsort: one block per 512-row bucket. Row-hist + scan -> [beg,end);
// degree counting sort -> rank (degree-homogeneous waves);
// edges stored as (col<<7 [byte offset], fp16(val) bits).
// ---------------------------------------------------------------------------
__global__ __launch_bounds__(512) void lg_rsort(const int2* __restrict__ tmp,
                                                const int* __restrict__ bcur,
                                                int2* __restrict__ sbe,
                                                int* __restrict__ srid,
                                                int2* __restrict__ cedge) {
    __shared__ int h[512];
    __shared__ int wsum[8];
    __shared__ int dh[64], dcur[64];
    const int b = blockIdx.x;
    const int t = threadIdx.x;
    const int s0 = b * CAP;
    const int s1 = bcur[b];
    h[t] = 0;
    if (t < 64) dh[t] = 0;
    __syncthreads();
    for (int s = s0 + t; s < s1; s += 512)
        atomicAdd(&h[(tmp[s].x >> 18) & BMSK], 1);
    __syncthreads();
    const int own = h[t];
    const int incl = block_incl_scan512(own, wsum, t);
    const int excl = incl - own;
    const int beg = s0 + excl;
    const int bin = own < 63 ? own : 63;
    atomicAdd(&dh[bin], 1);
    __syncthreads();
    if (t < 64) {
        int v = dh[t];
        int inc = v;
        #pragma unroll
        for (int o = 1; o < 64; o <<= 1) {
            int u = __shfl_up(inc, o, 64);
            if (t >= o) inc += u;
        }
        dcur[t] = inc - v;
    }
    __syncthreads();
    const int rank = atomicAdd(&dcur[bin], 1);
    const int r = (b << BSH) + t;
    const int slot = (b << BSH) + rank;
    sbe[slot] = make_int2(beg, beg + own);
    srid[slot] = (r < NTOT) ? r : -1;
    __syncthreads();
    h[t] = excl;
    __syncthreads();
    for (int s = s0 + t; s < s1; s += 512) {
        const int2 ev = tmp[s];
        const int rl = (ev.x >> 18) & BMSK;
        const int k = atomicAdd(&h[rl], 1);
        const float v = __int_as_float(ev.y);
        const __half hv = __float2half(v);
        const unsigned short hb = *(const unsigned short*)&hv;
        cedge[s0 + k] = make_int2((ev.x & 0x3FFFF) << 7, (int)(unsigned)hb);
    }
}

// ---------------------------------------------------------------------------
// dot: 8 dims (16B fp16) * val, fp32 accumulate via fdot2
// ---------------------------------------------------------------------------
__device__ __forceinline__ void dot8(float sum[8], const uint4& q, unsigned vh) {
#if __has_builtin(__builtin_amdgcn_fdot2)
    const half2_t vlo = u2h(vh);
    const half2_t vhi = u2h(vh << 16);
    const half2_t* hp = (const half2_t*)&q;
    #pragma unroll
    for (int k = 0; k < 4; ++k) {
        sum[2 * k]     = __builtin_amdgcn_fdot2(hp[k], vlo, sum[2 * k],     false);
        sum[2 * k + 1] = __builtin_amdgcn_fdot2(hp[k], vhi, sum[2 * k + 1], false);
    }
#else
    __half hv; *(unsigned short*)&hv = (unsigned short)(vh & 0xFFFF);
    const float v = __half2float(hv);
    const __half2* hp = (const __half2*)&q;
    #pragma unroll
    for (int k = 0; k < 4; ++k) {
        const float2 f = __half22float2(hp[k]);
        sum[2 * k]     += v * f.x;
        sum[2 * k + 1] += v * f.y;
    }
#endif
}

// ---------------------------------------------------------------------------
// gather core, 8-deep MLP + coalesced edge fetch: 8-lane group owns one row;
// lane d covers dims [8d,8d+8). Per 8-edge window: lane d loads edge it0+d
// (64B coalesced per group), __shfl distributes entries within the group,
// then all 8 table lines are issued before any dot consumes them.
// Clamped-index + masked-val makes over-reads past deg safe (adds 0).
// ---------------------------------------------------------------------------
__device__ __forceinline__ void row_gather8c(const int2* __restrict__ ce,
                                             const char* __restrict__ tb,
                                             int deg, int nit, int lane,
                                             float sum[8]) {
    #pragma unroll
    for (int k = 0; k < 8; ++k) sum[k] = 0.0f;
    if (nit <= 0) return;
    const int d  = lane & 7;
    const int gb = lane & 56;                 // group base lane
    const int degm1 = deg > 0 ? deg - 1 : 0;
    for (int it0 = 0; it0 < nit; it0 += 8) {
        const int myit  = it0 + d;
        const int myidx = myit < degm1 ? myit : degm1;
        const int2 myc  = ce[myidx];          // coalesced 64B per group
        unsigned vh[8];
        uint4 q[8];
        #pragma unroll
        for (int j = 0; j < 8; ++j) {
            const int src = gb + j;
            const unsigned colb = (unsigned)__shfl(myc.x, src, 64);
            const unsigned v    = (unsigned)__shfl(myc.y, src, 64);
            const bool valid = (it0 + j) < deg;
            vh[j] = valid ? v : 0u;
            q[j] = *(const uint4*)(tb + (valid ? colb : 0u));
        }
        #pragma unroll
        for (int j = 0; j < 8; ++j) dot8(sum, q[j], vh[j]);
    }
}

// mid layer: nxt = fp16(A * cur)
__global__ __launch_bounds__(256) void lg_gmid(const int2* __restrict__ sbe,
                                               const int* __restrict__ srid,
                                               const int2* __restrict__ cedge,
                                               const __half* __restrict__ cur,
                                               __half* __restrict__ nxt) {
    const int gid = blockIdx.x * 256 + threadIdx.x;
    const int lane = threadIdx.x & 63;
    const int slot = ((gid >> 6) << 3) + (lane >> 3);
    const int d = lane & 7;
    const int2 pe = sbe[slot];
    const int rid = srid[slot];
    const int deg = pe.y - pe.x;
    const int nit = __shfl(deg, 63, 64);      // wave max (degree-sorted)
    float s[8];
    row_gather8c(cedge + pe.x, (const char*)cur + d * 16, deg, nit, lane, s);
    if (rid >= 0) {
        __half2 o[4];
        #pragma unroll
        for (int k = 0; k < 4; ++k) o[k] = __floats2half2_rn(s[2 * k], s[2 * k + 1]);
        ((uint4*)(nxt + ((size_t)rid << 6)))[d] = *(const uint4*)o;
    }
}

// last layer, fused: acc = 0.25*(b0 + b1 + b2 + A*b2)   (fp32 output)
__global__ __launch_bounds__(256) void lg_glast(const int2* __restrict__ sbe,
                                                const int* __restrict__ srid,
                                                const int2* __restrict__ cedge,
                                                const __half* __restrict__ b0,
                                                const __half* __restrict__ b1,
                                                const __half* __restrict__ b2,
                                                float* __restrict__ acc) {
    const int gid = blockIdx.x * 256 + threadIdx.x;
    const int lane = threadIdx.x & 63;
    const int slot = ((gid >> 6) << 3) + (lane >> 3);
    const int d = lane & 7;
    const int2 pe = sbe[slot];
    const int rid = srid[slot];
    const int deg = pe.y - pe.x;
    const int nit = __shfl(deg, 63, 64);
    float s[8];
    row_gather8c(cedge + pe.x, (const char*)b2 + d * 16, deg, nit, lane, s);
    if (rid >= 0) {
        const size_t base = (size_t)rid << 6;
        const uint4 q0 = ((const uint4*)(b0 + base))[d];
        const uint4 q1 = ((const uint4*)(b1 + base))[d];
        const uint4 q2 = ((const uint4*)(b2 + base))[d];
        const __half2* h0 = (const __half2*)&q0;
        const __half2* h1 = (const __half2*)&q1;
        const __half2* h2 = (const __half2*)&q2;
        float out[8];
        #pragma unroll
        for (int k = 0; k < 4; ++k) {
            const float2 f0 = __half22float2(h0[k]);
            const float2 f1 = __half22float2(h1[k]);
            const float2 f2 = __half22float2(h2[k]);
            out[2 * k]     = 0.25f * (f0.x + f1.x + f2.x + s[2 * k]);
            out[2 * k + 1] = 0.25f * (f0.y + f1.y + f2.y + s[2 * k + 1]);
        }
        float* dst = acc + base + (size_t)d * 8;
        *(float4*)(dst)     = make_float4(out[0], out[1], out[2], out[3]);
        *(float4*)(dst + 4) = make_float4(out[4], out[5], out[6], out[7]);
    }
}

// ---------------------------------------------------------------------------
// Fallback (round-1) kernels: edge-parallel scatter with fp32 atomics
// ---------------------------------------------------------------------------
__global__ void lg_init2(const float* __restrict__ ue, const float* __restrict__ ie,
                         float* __restrict__ cur, float* __restrict__ acc) {
    const int total4 = NTOT * DIM / 4;
    const int ubound4 = NUSERS * DIM / 4;
    const float4* ue4 = (const float4*)ue;
    const float4* ie4 = (const float4*)ie;
    float4* cur4 = (float4*)cur;
    float4* acc4 = (float4*)acc;
    for (int i = blockIdx.x * blockDim.x + threadIdx.x; i < total4;
         i += gridDim.x * blockDim.x) {
        float4 v = (i < ubound4) ? ue4[i] : ie4[i - ubound4];
        cur4[i] = v;
        float4 a;
        a.x = 0.25f * v.x; a.y = 0.25f * v.y; a.z = 0.25f * v.z; a.w = 0.25f * v.w;
        acc4[i] = a;
    }
}

__global__ void lg_scatter(const float* __restrict__ cur, const float* __restrict__ vals,
                           const int* __restrict__ row, const int* __restrict__ col,
                           float* __restrict__ next) {
    const long long total = (long long)NNZ * 64;
    for (long long t = blockIdx.x * (long long)blockDim.x + threadIdx.x; t < total;
         t += (long long)gridDim.x * blockDim.x) {
        const int e    = (int)(t >> 6);
        const int lane = (int)(t & 63);
        const float m  = cur[(long long)col[e] * DIM + lane] * vals[e];
        atomicAdd(&next[(long long)row[e] * DIM + lane], m);
    }
}

__global__ void lg_axpy(const float* __restrict__ next, float* __restrict__ acc) {
    const int total4 = NTOT * DIM / 4;
    const float4* n4 = (const float4*)next;
    float4* a4 = (float4*)acc;
    for (int i = blockIdx.x * blockDim.x + threadIdx.x; i < total4;
         i += gridDim.x * blockDim.x) {
        float4 n = n4[i];
        float4 a = a4[i];
        a.x += 0.25f * n.x; a.y += 0.25f * n.y; a.z += 0.25f * n.z; a.w += 0.25f * n.w;
        a4[i] = a;
    }
}

extern "C" void kernel_launch(void* const* d_in, const int* in_sizes, int n_in,
                              void* d_out, int out_size, void* d_ws, size_t ws_size,
                              hipStream_t stream) {
    const float* ue   = (const float*)d_in[0];
    const float* ie   = (const float*)d_in[1];
    const float* vals = (const float*)d_in[2];
    const int*   row  = (const int*)d_in[3];
    const int*   col  = (const int*)d_in[4];

    float* acc = (float*)d_out;

    const size_t EMB = (size_t)NTOT * DIM;       // 9.6M elements

    // workspace layout
    __half* b0   = (__half*)d_ws;                // 19.2 MB
    __half* b1   = b0 + EMB;                     // 19.2 MB
    __half* b2   = b1 + EMB;                     // 19.2 MB
    int2* tmp    = (int2*)(b2 + EMB);            // NB*CAP int2 = 19.2 MB
    int2* cedge  = tmp + (size_t)NB * CAP;       // 19.2 MB
    int2* sbe    = cedge + (size_t)NB * CAP;     // NSLOTS int2 = 1.2 MB
    int*  srid   = (int*)(sbe + NSLOTS);         // 0.6 MB
    int*  bcur   = srid + NSLOTS;                // NB
    const size_t need = (size_t)((char*)(bcur + NB) - (char*)d_ws);   // ~97.8 MB

    if (ws_size >= need) {
        const int nchunks = (NNZ + CHUNK - 1) / CHUNK;   // 489
        const int gblocks = NSLOTS * 8 / 256;            // 4688, exact

        lg_inith<<<1024, 256, 0, stream>>>(ue, ie, b0);
        lg_binit<<<1, 512, 0, stream>>>(bcur);
        lg_part<<<nchunks, 512, 0, stream>>>(row, col, vals, bcur, tmp);
        lg_rsort<<<NB, 512, 0, stream>>>(tmp, bcur, sbe, srid, cedge);

        lg_gmid <<<gblocks, 256, 0, stream>>>(sbe, srid, cedge, b0, b1);
        lg_gmid <<<gblocks, 256, 0, stream>>>(sbe, srid, cedge, b1, b2);
        lg_glast<<<gblocks, 256, 0, stream>>>(sbe, srid, cedge, b0, b1, b2, acc);
    } else {
        // minimal fallback: round-1 scatter path (2 x 38.4 MB fp32)
        float* cur = (float*)d_ws;
        float* nxt = cur + EMB;
        const size_t buf_bytes = EMB * sizeof(float);
        lg_init2<<<1024, 256, 0, stream>>>(ue, ie, cur, acc);
        for (int l = 0; l < NLAYERS; ++l) {
            hipMemsetAsync(nxt, 0, buf_bytes, stream);
            lg_scatter<<<8192, 256, 0, stream>>>(cur, vals, row, col, nxt);
            lg_axpy<<<1024, 256, 0, stream>>>(nxt, acc);
            float* t = cur; cur = nxt; nxt = t;
        }
    }
}